// Round 5
// baseline (208.917 us; speedup 1.0000x reference)
//
#include <hip/hip_runtime.h>

// Until operator: r[t] = max( min(1,psi[t]), min(phi[t], r[t+1]) ), r[T] = -inf.
// f(x)=max(a,min(b,x)) closed under composition (f earlier in time):
//   (f o g): A = max(a_f, min(b_f, a_g)), B = min(b_f, b_g)
// float4 = 2 timesteps x 2 channels = one "pair entry". Row = 4096 entries,
// segment = 512 entries, NSEG=8 segments/row, one WAVE per segment.
//
// R5: two decoupled streaming kernels, ZERO __syncthreads.
//  A: per-segment summary (A,B per channel) -> d_ws   [8192 x float4]
//  B: carry = compose of right-neighbor summaries (registers), then
//     scan + apply + store. phi/psi re-read is L3-resident (128MiB < 256MiB).
// Wave-private LDS transpose (SoA G write, b128 group read) gives each lane
// 4 CONTIGUOUS entries -> one 6-step shuffle suffix-scan per 256-entry round.
// LDS reuse across rounds is safe: DS pipe is in-order per wave; fences stop
// compiler reordering. 4KiB LDS/wave, blocks of 256 -> 8 blocks/CU.

#define T_LEN  8192
#define ROW_F4 (T_LEN / 2)   // 4096 entries per row
#define SEG_F4 512           // entries per segment (one wave)
#define NSEG   8             // segments per row
#define BLK    256
#define WPB    (BLK / 64)    // waves per block = 4

__device__ __forceinline__ float rfl(float x) {
    return __int_as_float(__builtin_amdgcn_readfirstlane(__float_as_int(x)));
}

// Wave-level ordering fence for wave-private LDS reuse: blocks compiler
// motion; HW executes a wave's DS ops in issue order.
__device__ __forceinline__ void wave_lds_fence() {
    __asm__ volatile("" ::: "memory");
    __builtin_amdgcn_wave_barrier();
    __asm__ volatile("" ::: "memory");
}

// Pair-function of one entry (2 timesteps x 2 ch), SoA write at stride 256.
__device__ __forceinline__ void build_G(const float4& P, const float4& Q,
                                        float* base) {
    float v0x = fminf(1.f, Q.x), v0y = fminf(1.f, Q.y);
    float v1x = fminf(1.f, Q.z), v1y = fminf(1.f, Q.w);
    base[0]   = fmaxf(v0x, fminf(P.x, v1x));  // GAx
    base[256] = fmaxf(v0y, fminf(P.y, v1y));  // GAy
    base[512] = fminf(P.x, P.z);              // GBx
    base[768] = fminf(P.y, P.w);              // GBy
}

// Compose lane's 4 contiguous entries right-to-left, then 64-lane inclusive
// SUFFIX scan (toward lane 63). S[lane] = composition of group entries
// lane*4 .. 255 of this round.
__device__ __forceinline__ void compose_scan(
    const float4& gax, const float4& gay, const float4& gbx, const float4& gby,
    int lane, float& Sax, float& Say, float& Sbx, float& Sby)
{
    const float NEG = -__builtin_huge_valf();
    const float POS =  __builtin_huge_valf();
    float hax = gax.w, hay = gay.w, hbx = gbx.w, hby = gby.w;
    hax = fmaxf(gax.z, fminf(gbx.z, hax));
    hay = fmaxf(gay.z, fminf(gby.z, hay));
    hbx = fminf(gbx.z, hbx);
    hby = fminf(gby.z, hby);
    hax = fmaxf(gax.y, fminf(gbx.y, hax));
    hay = fmaxf(gay.y, fminf(gby.y, hay));
    hbx = fminf(gbx.y, hbx);
    hby = fminf(gby.y, hby);
    hax = fmaxf(gax.x, fminf(gbx.x, hax));
    hay = fmaxf(gay.x, fminf(gby.x, hay));
    hbx = fminf(gbx.x, hbx);
    hby = fminf(gby.x, hby);
#pragma unroll
    for (int off = 1; off < 64; off <<= 1) {
        float qax = __shfl_down(hax, off), qay = __shfl_down(hay, off);
        float qbx = __shfl_down(hbx, off), qby = __shfl_down(hby, off);
        bool  val = (lane + off) < 64;
        qax = val ? qax : NEG;  qay = val ? qay : NEG;
        qbx = val ? qbx : POS;  qby = val ? qby : POS;
        hax = fmaxf(hax, fminf(hbx, qax));
        hay = fmaxf(hay, fminf(hby, qay));
        hbx = fminf(hbx, qbx);
        hby = fminf(hby, qby);
    }
    Sax = hax; Say = hay; Sbx = hbx; Sby = hby;
}

// ---------------- Kernel A: per-segment summaries ----------------
__global__ __launch_bounds__(BLK, 4) void until_sum(
    const float* __restrict__ phi, const float* __restrict__ psi,
    float4* __restrict__ ws4)
{
    const int wid  = blockIdx.x * WPB + (threadIdx.x >> 6);  // global wave id
    const int row  = wid >> 3;
    const int w    = wid & 7;
    const int lane = threadIdx.x & 63;

    const size_t segf4 = (size_t)row * ROW_F4 + (size_t)w * SEG_F4;
    const float4* __restrict__ phi4 = (const float4*)phi + segf4;
    const float4* __restrict__ psi4 = (const float4*)psi + segf4;

    __shared__ alignas(16) float lds[WPB * 1024];
    float* wl = lds + (threadIdx.x >> 6) * 1024;

    // burst all 16 loads
    float4 P[8], Q[8];
#pragma unroll
    for (int k = 0; k < 8; ++k) {
        P[k] = phi4[k * 64 + lane];
        Q[k] = psi4[k * 64 + lane];
    }

    float Sax[2], Say[2], Sbx[2], Sby[2];
#pragma unroll
    for (int r = 0; r < 2; ++r) {
#pragma unroll
        for (int kl = 0; kl < 4; ++kl)
            build_G(P[r * 4 + kl], Q[r * 4 + kl], wl + kl * 64 + lane);
        wave_lds_fence();
        float4 gax = *(const float4*)(wl + 0 * 256 + lane * 4);
        float4 gay = *(const float4*)(wl + 1 * 256 + lane * 4);
        float4 gbx = *(const float4*)(wl + 2 * 256 + lane * 4);
        float4 gby = *(const float4*)(wl + 3 * 256 + lane * 4);
        wave_lds_fence();   // WAR guard: next round rewrites same region
        compose_scan(gax, gay, gbx, gby, lane, Sax[r], Say[r], Sbx[r], Sby[r]);
    }
    // lane 0 holds round summaries R0, R1; W = R0 o R1
    if (lane == 0) {
        float wax = fmaxf(Sax[0], fminf(Sbx[0], Sax[1]));
        float way = fmaxf(Say[0], fminf(Sby[0], Say[1]));
        float wbx = fminf(Sbx[0], Sbx[1]);
        float wby = fminf(Sby[0], Sby[1]);
        ws4[wid] = make_float4(wax, way, wbx, wby);
    }
}

// ---------------- Kernel B: carry + scan + apply ----------------
__global__ __launch_bounds__(BLK, 4) void until_apply(
    const float* __restrict__ phi, const float* __restrict__ psi,
    const float4* __restrict__ ws4, float* __restrict__ out)
{
    const int wid  = blockIdx.x * WPB + (threadIdx.x >> 6);
    const int row  = wid >> 3;
    const int w    = wid & 7;
    const int lane = threadIdx.x & 63;
    const float NEG = -__builtin_huge_valf();

    const size_t segf4 = (size_t)row * ROW_F4 + (size_t)w * SEG_F4;
    const float4* __restrict__ phi4 = (const float4*)phi + segf4;
    const float4* __restrict__ psi4 = (const float4*)psi + segf4;
    float4* __restrict__ out4 = (float4*)out + segf4;

    __shared__ alignas(16) float lds[WPB * 1024];
    float* wl = lds + (threadIdx.x >> 6) * 1024;

    // carry entering this segment's right edge: apply W_7 first, ... W_{w+1}
    const float4* __restrict__ sums = ws4 + (size_t)row * NSEG;
    float rcx = NEG, rcy = NEG;
    for (int j = NSEG - 1; j > w; --j) {
        float4 s = sums[j];
        rcx = fmaxf(s.x, fminf(s.z, rcx));
        rcy = fmaxf(s.y, fminf(s.w, rcy));
    }

    // burst all 16 loads (L3-resident after kernel A)
    float4 P[8], Q[8];
#pragma unroll
    for (int k = 0; k < 8; ++k) {
        P[k] = phi4[k * 64 + lane];
        Q[k] = psi4[k * 64 + lane];
    }

    float4 GAx[2], GAy[2], GBx[2], GBy[2];
    float  Sax[2], Say[2], Sbx[2], Sby[2];
#pragma unroll
    for (int r = 0; r < 2; ++r) {
#pragma unroll
        for (int kl = 0; kl < 4; ++kl)
            build_G(P[r * 4 + kl], Q[r * 4 + kl], wl + kl * 64 + lane);
        wave_lds_fence();
        GAx[r] = *(const float4*)(wl + 0 * 256 + lane * 4);
        GAy[r] = *(const float4*)(wl + 1 * 256 + lane * 4);
        GBx[r] = *(const float4*)(wl + 2 * 256 + lane * 4);
        GBy[r] = *(const float4*)(wl + 3 * 256 + lane * 4);
        wave_lds_fence();   // WAR guard before next round / carry writes
        compose_scan(GAx[r], GAy[r], GBx[r], GBy[r], lane,
                     Sax[r], Say[r], Sbx[r], Sby[r]);
    }

    // round carries: round 1 is applied first in time-reverse
    float R1ax = rfl(Sax[1]), R1ay = rfl(Say[1]);
    float R1bx = rfl(Sbx[1]), R1by = rfl(Sby[1]);
    float rinx[2], riny[2];
    rinx[1] = rcx;
    riny[1] = rcy;
    rinx[0] = fmaxf(R1ax, fminf(R1bx, rcx));
    riny[0] = fmaxf(R1ay, fminf(R1by, rcy));

    // per-entry carries -> LDS:  CX[e] at wl[e], CY[e] at wl[512+e]
#pragma unroll
    for (int r = 0; r < 2; ++r) {
        // y = r-value at lane's group LEFT edge = S_r[lane](r_in)
        float yx = fmaxf(Sax[r], fminf(Sbx[r], rinx[r]));
        float yy = fmaxf(Say[r], fminf(Sby[r], riny[r]));
        // carry entering lane's rightmost entry = y_{lane+1} (lane63: r_in)
        float cx = __shfl_down(yx, 1), cy = __shfl_down(yy, 1);
        if (lane == 63) { cx = rinx[r]; cy = riny[r]; }
        float4 CX, CY;
        CX.w = cx;
        CY.w = cy;
        CX.z = fmaxf(GAx[r].w, fminf(GBx[r].w, CX.w));
        CY.z = fmaxf(GAy[r].w, fminf(GBy[r].w, CY.w));
        CX.y = fmaxf(GAx[r].z, fminf(GBx[r].z, CX.z));
        CY.y = fmaxf(GAy[r].z, fminf(GBy[r].z, CY.z));
        CX.x = fmaxf(GAx[r].y, fminf(GBx[r].y, CX.y));
        CY.x = fmaxf(GAy[r].y, fminf(GBy[r].y, CY.y));
        *(float4*)(wl +       r * 256 + lane * 4) = CX;
        *(float4*)(wl + 512 + r * 256 + lane * 4) = CY;
    }
    wave_lds_fence();

    // emit outputs: reload (L1-warm) + per-entry carry from LDS
#pragma unroll
    for (int k = 0; k < 8; ++k) {
        const int e = k * 64 + lane;
        float4 P2 = phi4[e];
        float4 Q2 = psi4[e];
        float cx = wl[e];
        float cy = wl[512 + e];
        float r1x = fmaxf(fminf(1.f, Q2.z), fminf(P2.z, cx));
        float r1y = fmaxf(fminf(1.f, Q2.w), fminf(P2.w, cy));
        float r0x = fmaxf(fminf(1.f, Q2.x), fminf(P2.x, r1x));
        float r0y = fmaxf(fminf(1.f, Q2.y), fminf(P2.y, r1y));
        out4[e] = make_float4(r0x, r0y, r1x, r1y);
    }
}

extern "C" void kernel_launch(void* const* d_in, const int* in_sizes, int n_in,
                              void* d_out, int out_size, void* d_ws, size_t ws_size,
                              hipStream_t stream) {
    const float* phi = (const float*)d_in[0];
    const float* psi = (const float*)d_in[1];
    float* out = (float*)d_out;
    float4* ws4 = (float4*)d_ws;                 // 8192 * 16B = 128 KiB
    const int Bn = in_sizes[0] / (T_LEN * 2);    // = 1024
    const int nwaves = Bn * NSEG;                // 8192
    const int grid = nwaves / WPB;               // 2048
    until_sum<<<grid, BLK, 0, stream>>>(phi, psi, ws4);
    until_apply<<<grid, BLK, 0, stream>>>(phi, psi, ws4, out);
}